// Round 2
// baseline (580.835 us; speedup 1.0000x reference)
//
#include <hip/hip_runtime.h>

#define BB 8
#define HH 256
#define WW 256
#define CC 128
#define HW (HH*WW)
#define NP (BB*HW)          // 524288 pixels
#define THRESHOLD 0.8f
#define EPSV 1e-3f

// ---------------- K1: channel max/mean pool. One wave (64 lanes) per pixel.
// Block 0 also zeroes acc(4096)+cnt(8) for the later passes (stream-ordered).
__global__ __launch_bounds__(256) void k_pool(const float* __restrict__ in,
                                              float2* __restrict__ pooled,
                                              float* __restrict__ zbuf) {
    if (blockIdx.x == 0) {
        for (int i = threadIdx.x; i < 4104; i += 256) zbuf[i] = 0.0f;
    }
    int p    = blockIdx.x * 4 + (threadIdx.x >> 6);   // pixel index
    int lane = threadIdx.x & 63;
    const float2 v = *reinterpret_cast<const float2*>(in + (size_t)p * CC + lane * 2);
    float mx = fmaxf(v.x, v.y);
    float sm = v.x + v.y;
#pragma unroll
    for (int m = 32; m >= 1; m >>= 1) {
        mx = fmaxf(mx, __shfl_xor(mx, m));
        sm += __shfl_xor(sm, m);
    }
    if (lane == 0) pooled[p] = make_float2(mx, sm * (1.0f / 128.0f));
}

// ---------------- K2: fused 3x3 convs. 32x32 tile per block, x kept in LDS
// (34x34 with halo). Produces mask, (beta,gamma) packed, and per-batch count.
__global__ __launch_bounds__(256) void k_mask(const float2* __restrict__ pooled,
                                              const float* __restrict__ w_sr,
                                              const float* __restrict__ b_sr,
                                              const float* __restrict__ w_gamma,
                                              const float* __restrict__ b_gamma,
                                              const float* __restrict__ w_beta,
                                              const float* __restrict__ b_beta,
                                              float* __restrict__ mask,
                                              float2* __restrict__ bg,
                                              float* __restrict__ cnt) {
    int b    = blockIdx.x >> 6;          // 64 tiles per batch (8x8)
    int tile = blockIdx.x & 63;
    int th0  = (tile >> 3) * 32;
    int tw0  = (tile & 7) * 32;
    __shared__ float xs[34][35];
    __shared__ float csh;
    if (threadIdx.x == 0) csh = 0.0f;

    float wsr[18], wg[9], wb[9];
#pragma unroll
    for (int i = 0; i < 18; ++i) wsr[i] = w_sr[i];
#pragma unroll
    for (int i = 0; i < 9; ++i) { wg[i] = w_gamma[i]; wb[i] = w_beta[i]; }
    float bsr = b_sr[0], bg0 = b_gamma[0], bb0 = b_beta[0];

    // x = sigmoid(conv_sr(pooled)) on the 34x34 halo tile; 0 outside image.
    for (int i = threadIdx.x; i < 34 * 34; i += 256) {
        int ly = i / 34, lx = i - ly * 34;
        int h = th0 + ly - 1, w = tw0 + lx - 1;
        float val = 0.0f;
        if ((unsigned)h < HH && (unsigned)w < WW) {
            float acc = bsr;
#pragma unroll
            for (int kh = 0; kh < 3; ++kh) {
                int hh = h + kh - 1;
                if ((unsigned)hh >= HH) continue;
#pragma unroll
                for (int kw = 0; kw < 3; ++kw) {
                    int ww = w + kw - 1;
                    if ((unsigned)ww >= WW) continue;
                    float2 pv = pooled[(size_t)b * HW + hh * WW + ww];
                    acc += pv.x * wsr[(kh * 3 + kw) * 2 + 0] + pv.y * wsr[(kh * 3 + kw) * 2 + 1];
                }
            }
            val = 1.0f / (1.0f + expf(-acc));
        }
        xs[ly][lx] = val;
    }
    __syncthreads();

    // gamma/beta = conv(x); mask = x > THRESHOLD on the 32x32 core.
    float csum = 0.0f;
    for (int i = threadIdx.x; i < 1024; i += 256) {
        int ty = i >> 5, tx = i & 31;
        float xc = xs[ty + 1][tx + 1];
        float m = (xc > THRESHOLD) ? 1.0f : 0.0f;
        csum += m;
        float ag = bg0, ab = bb0;
#pragma unroll
        for (int kh = 0; kh < 3; ++kh)
#pragma unroll
            for (int kw = 0; kw < 3; ++kw) {
                float xv = xs[ty + kh][tx + kw];
                ag += xv * wg[kh * 3 + kw];
                ab += xv * wb[kh * 3 + kw];
            }
        size_t p = (size_t)b * HW + (size_t)(th0 + ty) * WW + (tw0 + tx);
        mask[p] = m;
        bg[p] = make_float2(ab, ag);   // (beta, gamma)
    }
    atomicAdd(&csh, csum);
    __syncthreads();
    if (threadIdx.x == 0) atomicAdd(&cnt[b], csh);
}

// ---------------- K3: per-(B,C) masked moments, float4 loads (1KB/wave).
// acc layout: [0]=sum_v, [1024]=sumsq_v, [2048]=sum_m, [3072]=sumsq_m
__global__ __launch_bounds__(256) void k_moments(const float* __restrict__ in,
                                                 const float* __restrict__ mask,
                                                 float* __restrict__ acc) {
    int b     = blockIdx.x >> 7;     // 128 chunks of 512 px per batch
    int chunk = blockIdx.x & 127;
    int c4    = threadIdx.x & 31;    // channel group: 4 channels
    int pg    = threadIdx.x >> 5;    // pixel slot 0..7
    float4 sv = make_float4(0, 0, 0, 0), ssv = sv, sm = sv, ssm = sv;
    int pbase = chunk * 512;
    for (int i = 0; i < 64; ++i) {
        int pl = pbase + i * 8 + pg;
        size_t p = (size_t)b * HW + pl;
        float m = mask[p];                                   // uniform per 32-lane group
        const float4 v = *reinterpret_cast<const float4*>(in + p * CC + c4 * 4);
        float4 v2 = make_float4(v.x * v.x, v.y * v.y, v.z * v.z, v.w * v.w);
        if (m > 0.5f) {
            sv.x += v.x; sv.y += v.y; sv.z += v.z; sv.w += v.w;
            ssv.x += v2.x; ssv.y += v2.y; ssv.z += v2.z; ssv.w += v2.w;
        } else {
            sm.x += v.x; sm.y += v.y; sm.z += v.z; sm.w += v.w;
            ssm.x += v2.x; ssm.y += v2.y; ssm.z += v2.z; ssm.w += v2.w;
        }
    }
    __shared__ float4 sh[4][8][32];   // 16 KB
    sh[0][pg][c4] = sv; sh[1][pg][c4] = ssv; sh[2][pg][c4] = sm; sh[3][pg][c4] = ssm;
    __syncthreads();
    int t = threadIdx.x;
    if (t < 128) {
        int arr = t >> 5, c = t & 31;
        float4 s = sh[arr][0][c];
#pragma unroll
        for (int j = 1; j < 8; ++j) {
            float4 u = sh[arr][j][c];
            s.x += u.x; s.y += u.y; s.z += u.z; s.w += u.w;
        }
        float* dst = acc + arr * 1024 + b * 128 + c * 4;
        atomicAdd(dst + 0, s.x);
        atomicAdd(dst + 1, s.y);
        atomicAdd(dst + 2, s.z);
        atomicAdd(dst + 3, s.w);
    }
}

// ---------------- K3.5: sums -> mu, 1/sqrt(sig+eps), per region
// stats layout: [0]=mu_v, [1024]=rs_v, [2048]=mu_m, [3072]=rs_m
__global__ void k_stats(const float* __restrict__ acc, const float* __restrict__ cnt,
                        float* __restrict__ stats) {
    int i = blockIdx.x * 256 + threadIdx.x;
    if (i >= 1024) return;
    int b = i >> 7;
    float cv = cnt[b];
    float cm = (float)HW - cv;
    float s_v = acc[i], ss_v = acc[1024 + i], s_m = acc[2048 + i], ss_m = acc[3072 + i];
    float fs_v = cv + EPSV;
    float mu_v = s_v / fs_v;
    float sig_v = (ss_v - 2.f * mu_v * s_v + mu_v * mu_v * cv) / fs_v;
    float fs_m = cm + EPSV;
    float mu_m = s_m / fs_m;
    float sig_m = (ss_m - 2.f * mu_m * s_m + mu_m * mu_m * cm) / fs_m;
    stats[i]        = mu_v;
    stats[1024 + i] = 1.0f / sqrtf(sig_v + EPSV);
    stats[2048 + i] = mu_m;
    stats[3072 + i] = 1.0f / sqrtf(sig_m + EPSV);
}

// ---------------- K4: apply. One float4 per thread, branchless stats select.
__global__ __launch_bounds__(256) void k_apply(const float* __restrict__ in,
                                               const float* __restrict__ mask,
                                               const float2* __restrict__ bg,
                                               const float* __restrict__ stats,
                                               float* __restrict__ out) {
    size_t idx = (size_t)blockIdx.x * 256 + threadIdx.x;  // float4 index
    size_t p = idx >> 5;                                  // 32 float4 per pixel
    int c4 = (int)(idx & 31);
    int b = (int)(p >> 16);
    const float4 v = reinterpret_cast<const float4*>(in)[idx];
    float m   = mask[p];
    float2 bgv = bg[p];
    float be = bgv.x, ga = bgv.y;
    int off = (m > 0.5f) ? 0 : 2048;
    int si = off + b * 128 + c4 * 4;
    const float4 mu = *reinterpret_cast<const float4*>(stats + si);
    const float4 rs = *reinterpret_cast<const float4*>(stats + si + 1024);
    float4 o;
    o.x = (v.x - mu.x) * rs.x * be + ga;
    o.y = (v.y - mu.y) * rs.y * be + ga;
    o.z = (v.z - mu.z) * rs.z * be + ga;
    o.w = (v.w - mu.w) * rs.w * be + ga;
    reinterpret_cast<float4*>(out)[idx] = o;
}

extern "C" void kernel_launch(void* const* d_in, const int* in_sizes, int n_in,
                              void* d_out, int out_size, void* d_ws, size_t ws_size,
                              hipStream_t stream) {
    const float* in      = (const float*)d_in[0];
    const float* w_sr    = (const float*)d_in[1];
    const float* b_sr    = (const float*)d_in[2];
    const float* w_gamma = (const float*)d_in[3];
    const float* b_gamma = (const float*)d_in[4];
    const float* w_beta  = (const float*)d_in[5];
    const float* b_beta  = (const float*)d_in[6];
    float* out = (float*)d_out;
    float* ws  = (float*)d_ws;

    float2* pooled = (float2*)ws;                     // 2*NP floats
    float*  mask   = ws + 2 * (size_t)NP;             // NP
    float2* bg     = (float2*)(ws + 3 * (size_t)NP);  // 2*NP (beta,gamma)
    float*  acc    = ws + 5 * (size_t)NP;             // 4096
    float*  cnt    = acc + 4096;                      // 8
    float*  stats  = cnt + 8;                         // 4096 (16B-aligned)

    k_pool   <<<NP / 4,  256, 0, stream>>>(in, pooled, acc);   // acc..cnt zeroed by block 0
    k_mask   <<<BB * 64, 256, 0, stream>>>(pooled, w_sr, b_sr, w_gamma, b_gamma,
                                           w_beta, b_beta, mask, bg, cnt);
    k_moments<<<BB * 128, 256, 0, stream>>>(in, mask, acc);
    k_stats  <<<4, 256, 0, stream>>>(acc, cnt, stats);
    k_apply  <<<(int)((size_t)NP * CC / 4 / 256), 256, 0, stream>>>(in, mask, bg, stats, out);
}

// Round 6
// 552.342 us; speedup vs baseline: 1.0516x; 1.0516x over previous
//
#include <hip/hip_runtime.h>

#define BB 8
#define HH 256
#define WW 256
#define CC 128
#define HW (HH*WW)
#define NP (BB*HW)          // 524288 pixels
#define THRESHOLD 0.8f
#define EPSV 1e-3f

// ---------------- Pass A: channel max/mean pool + unconditional per-(b,c)
// sums T=sum(v), TS=sum(v^2). 128 chunks/batch, 512 px/chunk.
// Thread layout: c4 = tid&31 (4 channels), pg = tid>>5 (pixel slot 0..7).
__global__ __launch_bounds__(256) void k_pool(const float* __restrict__ in,
                                              float2* __restrict__ pooled,
                                              float* __restrict__ accT,
                                              float* __restrict__ accTS) {
    int b     = blockIdx.x >> 7;
    int chunk = blockIdx.x & 127;
    int c4    = threadIdx.x & 31;
    int pg    = threadIdx.x >> 5;
    int base  = chunk * 512;
    float4 tT  = make_float4(0, 0, 0, 0), tTS = tT;
    for (int i = 0; i < 64; ++i) {
        int pl = base + i * 8 + pg;
        size_t p = (size_t)b * HW + pl;
        const float4 v = *reinterpret_cast<const float4*>(in + p * CC + c4 * 4);
        tT.x += v.x; tT.y += v.y; tT.z += v.z; tT.w += v.w;
        tTS.x += v.x * v.x; tTS.y += v.y * v.y; tTS.z += v.z * v.z; tTS.w += v.w * v.w;
        // per-pixel channel reduction across the 32-lane group
        float mx = fmaxf(fmaxf(v.x, v.y), fmaxf(v.z, v.w));
        float sm = v.x + v.y + v.z + v.w;
#pragma unroll
        for (int msk = 16; msk >= 1; msk >>= 1) {
            mx = fmaxf(mx, __shfl_xor(mx, msk));
            sm += __shfl_xor(sm, msk);
        }
        if (c4 == 0) pooled[p] = make_float2(mx, sm * (1.0f / 128.0f));
    }
    __shared__ float4 shT[8][32];
    __shared__ float4 shS[8][32];
    shT[pg][c4] = tT;
    shS[pg][c4] = tTS;
    __syncthreads();
    int t = threadIdx.x;
    if (t < 64) {
        int arr = t >> 5, c = t & 31;
        float4 s = arr ? shS[0][c] : shT[0][c];
#pragma unroll
        for (int j = 1; j < 8; ++j) {
            float4 u = arr ? shS[j][c] : shT[j][c];
            s.x += u.x; s.y += u.y; s.z += u.z; s.w += u.w;
        }
        float* dst = (arr ? accTS : accT) + b * 128 + c * 4;
        atomicAdd(dst + 0, s.x);
        atomicAdd(dst + 1, s.y);
        atomicAdd(dst + 2, s.z);
        atomicAdd(dst + 3, s.w);
    }
}

// ---------------- K2: fused 3x3 convs. 32x32 tile per block, x kept in LDS
// (34x34 with halo). Produces mask, (beta,gamma) packed, and per-batch count.
__global__ __launch_bounds__(256) void k_mask(const float2* __restrict__ pooled,
                                              const float* __restrict__ w_sr,
                                              const float* __restrict__ b_sr,
                                              const float* __restrict__ w_gamma,
                                              const float* __restrict__ b_gamma,
                                              const float* __restrict__ w_beta,
                                              const float* __restrict__ b_beta,
                                              float* __restrict__ mask,
                                              float2* __restrict__ bg,
                                              float* __restrict__ cnt) {
    int b    = blockIdx.x >> 6;          // 64 tiles per batch (8x8)
    int tile = blockIdx.x & 63;
    int th0  = (tile >> 3) * 32;
    int tw0  = (tile & 7) * 32;
    __shared__ float xs[34][35];
    __shared__ float csh;
    if (threadIdx.x == 0) csh = 0.0f;

    float wsr[18], wg[9], wb[9];
#pragma unroll
    for (int i = 0; i < 18; ++i) wsr[i] = w_sr[i];
#pragma unroll
    for (int i = 0; i < 9; ++i) { wg[i] = w_gamma[i]; wb[i] = w_beta[i]; }
    float bsr = b_sr[0], bg0 = b_gamma[0], bb0 = b_beta[0];

    // x = sigmoid(conv_sr(pooled)) on the 34x34 halo tile; 0 outside image.
    for (int i = threadIdx.x; i < 34 * 34; i += 256) {
        int ly = i / 34, lx = i - ly * 34;
        int h = th0 + ly - 1, w = tw0 + lx - 1;
        float val = 0.0f;
        if ((unsigned)h < HH && (unsigned)w < WW) {
            float acc = bsr;
#pragma unroll
            for (int kh = 0; kh < 3; ++kh) {
                int hh = h + kh - 1;
                if ((unsigned)hh >= HH) continue;
#pragma unroll
                for (int kw = 0; kw < 3; ++kw) {
                    int ww = w + kw - 1;
                    if ((unsigned)ww >= WW) continue;
                    float2 pv = pooled[(size_t)b * HW + hh * WW + ww];
                    acc += pv.x * wsr[(kh * 3 + kw) * 2 + 0] + pv.y * wsr[(kh * 3 + kw) * 2 + 1];
                }
            }
            val = 1.0f / (1.0f + expf(-acc));
        }
        xs[ly][lx] = val;
    }
    __syncthreads();

    // gamma/beta = conv(x); mask = x > THRESHOLD on the 32x32 core.
    float csum = 0.0f;
    for (int i = threadIdx.x; i < 1024; i += 256) {
        int ty = i >> 5, tx = i & 31;
        float xc = xs[ty + 1][tx + 1];
        float m = (xc > THRESHOLD) ? 1.0f : 0.0f;
        csum += m;
        float ag = bg0, ab = bb0;
#pragma unroll
        for (int kh = 0; kh < 3; ++kh)
#pragma unroll
            for (int kw = 0; kw < 3; ++kw) {
                float xv = xs[ty + kh][tx + kw];
                ag += xv * wg[kh * 3 + kw];
                ab += xv * wb[kh * 3 + kw];
            }
        size_t p = (size_t)b * HW + (size_t)(th0 + ty) * WW + (tw0 + tx);
        mask[p] = m;
        bg[p] = make_float2(ab, ag);   // (beta, gamma)
    }
    atomicAdd(&csh, csum);
    __syncthreads();
    if (threadIdx.x == 0) atomicAdd(&cnt[b], csh);
}

// ---------------- Pass B: sparse moments — only pixels of the SMALLER region
// are read; the other region's sums derive from T/TS by subtraction.
// accV/accVS hold the target-region sums.
__global__ __launch_bounds__(256) void k_moments(const float* __restrict__ in,
                                                 const float* __restrict__ mask,
                                                 const float* __restrict__ cnt,
                                                 float* __restrict__ accV,
                                                 float* __restrict__ accVS) {
    int b     = blockIdx.x >> 7;     // 128 chunks of 512 px per batch
    int chunk = blockIdx.x & 127;
    int c4    = threadIdx.x & 31;
    int pg    = threadIdx.x >> 5;
    bool tgt1 = cnt[b] <= (float)(HW / 2);   // accumulate mask==1 iff it's the smaller region
    float4 sv = make_float4(0, 0, 0, 0), ssv = sv;
    int pbase = chunk * 512;
    for (int i = 0; i < 64; ++i) {
        int pl = pbase + i * 8 + pg;
        size_t p = (size_t)b * HW + pl;
        bool mv = mask[p] > 0.5f;            // uniform per 32-lane group
        if (mv == tgt1) {
            const float4 v = *reinterpret_cast<const float4*>(in + p * CC + c4 * 4);
            sv.x += v.x; sv.y += v.y; sv.z += v.z; sv.w += v.w;
            ssv.x += v.x * v.x; ssv.y += v.y * v.y; ssv.z += v.z * v.z; ssv.w += v.w * v.w;
        }
    }
    __shared__ float4 shV[8][32];
    __shared__ float4 shS[8][32];
    shV[pg][c4] = sv;
    shS[pg][c4] = ssv;
    __syncthreads();
    int t = threadIdx.x;
    if (t < 64) {
        int arr = t >> 5, c = t & 31;
        float4 s = arr ? shS[0][c] : shV[0][c];
#pragma unroll
        for (int j = 1; j < 8; ++j) {
            float4 u = arr ? shS[j][c] : shV[j][c];
            s.x += u.x; s.y += u.y; s.z += u.z; s.w += u.w;
        }
        float* dst = (arr ? accVS : accV) + b * 128 + c * 4;
        atomicAdd(dst + 0, s.x);
        atomicAdd(dst + 1, s.y);
        atomicAdd(dst + 2, s.z);
        atomicAdd(dst + 3, s.w);
    }
}

// ---------------- K3.5: sums -> mu, 1/sqrt(sig+eps), per region
// stats layout: [0]=mu_v, [1024]=rs_v, [2048]=mu_m, [3072]=rs_m
__global__ void k_stats(const float* __restrict__ accT, const float* __restrict__ accTS,
                        const float* __restrict__ accV, const float* __restrict__ accVS,
                        const float* __restrict__ cnt, float* __restrict__ stats) {
    int i = blockIdx.x * 256 + threadIdx.x;
    if (i >= 1024) return;
    int b = i >> 7;
    float cv = cnt[b];                 // count of mask==1
    float cm = (float)HW - cv;
    bool tgt1 = cv <= (float)(HW / 2);
    float T = accT[i], TS = accTS[i], s_t = accV[i], ss_t = accVS[i];
    float s_v, ss_v, s_m, ss_m;
    if (tgt1) { s_v = s_t; ss_v = ss_t; s_m = T - s_t; ss_m = TS - ss_t; }
    else      { s_m = s_t; ss_m = ss_t; s_v = T - s_t; ss_v = TS - ss_t; }
    float fs_v = cv + EPSV;
    float mu_v = s_v / fs_v;
    float sig_v = (ss_v - 2.f * mu_v * s_v + mu_v * mu_v * cv) / fs_v;
    float fs_m = cm + EPSV;
    float mu_m = s_m / fs_m;
    float sig_m = (ss_m - 2.f * mu_m * s_m + mu_m * mu_m * cm) / fs_m;
    stats[i]        = mu_v;
    stats[1024 + i] = 1.0f / sqrtf(sig_v + EPSV);
    stats[2048 + i] = mu_m;
    stats[3072 + i] = 1.0f / sqrtf(sig_m + EPSV);
}

// ---------------- K4: apply. One float4 per thread, branchless stats select.
__global__ __launch_bounds__(256) void k_apply(const float* __restrict__ in,
                                               const float* __restrict__ mask,
                                               const float2* __restrict__ bg,
                                               const float* __restrict__ stats,
                                               float* __restrict__ out) {
    size_t idx = (size_t)blockIdx.x * 256 + threadIdx.x;  // float4 index
    size_t p = idx >> 5;                                  // 32 float4 per pixel
    int c4 = (int)(idx & 31);
    int b = (int)(p >> 16);
    const float4 v = reinterpret_cast<const float4*>(in)[idx];
    float m    = mask[p];
    float2 bgv = bg[p];
    float be = bgv.x, ga = bgv.y;
    int off = (m > 0.5f) ? 0 : 2048;
    int si = off + b * 128 + c4 * 4;
    const float4 mu = *reinterpret_cast<const float4*>(stats + si);
    const float4 rs = *reinterpret_cast<const float4*>(stats + si + 1024);
    float4 o;
    o.x = (v.x - mu.x) * rs.x * be + ga;
    o.y = (v.y - mu.y) * rs.y * be + ga;
    o.z = (v.z - mu.z) * rs.z * be + ga;
    o.w = (v.w - mu.w) * rs.w * be + ga;
    reinterpret_cast<float4*>(out)[idx] = o;
}

extern "C" void kernel_launch(void* const* d_in, const int* in_sizes, int n_in,
                              void* d_out, int out_size, void* d_ws, size_t ws_size,
                              hipStream_t stream) {
    const float* in      = (const float*)d_in[0];
    const float* w_sr    = (const float*)d_in[1];
    const float* b_sr    = (const float*)d_in[2];
    const float* w_gamma = (const float*)d_in[3];
    const float* b_gamma = (const float*)d_in[4];
    const float* w_beta  = (const float*)d_in[5];
    const float* b_beta  = (const float*)d_in[6];
    float* out = (float*)d_out;
    float* ws  = (float*)d_ws;

    float2* pooled = (float2*)ws;                     // 2*NP floats
    float*  mask   = ws + 2 * (size_t)NP;             // NP
    float2* bg     = (float2*)(ws + 3 * (size_t)NP);  // 2*NP (beta,gamma)
    float*  accT   = ws + 5 * (size_t)NP;             // 1024
    float*  accTS  = accT + 1024;                     // 1024
    float*  accV   = accTS + 1024;                    // 1024
    float*  accVS  = accV + 1024;                     // 1024
    float*  cnt    = accVS + 1024;                    // 8
    float*  stats  = cnt + 8;                         // 4096 (16B-aligned)

    hipMemsetAsync(accT, 0, (4096 + 8) * sizeof(float), stream);

    k_pool   <<<BB * 128, 256, 0, stream>>>(in, pooled, accT, accTS);
    k_mask   <<<BB * 64, 256, 0, stream>>>(pooled, w_sr, b_sr, w_gamma, b_gamma,
                                           w_beta, b_beta, mask, bg, cnt);
    k_moments<<<BB * 128, 256, 0, stream>>>(in, mask, cnt, accV, accVS);
    k_stats  <<<4, 256, 0, stream>>>(accT, accTS, accV, accVS, cnt, stats);
    k_apply  <<<(int)((size_t)NP * CC / 4 / 256), 256, 0, stream>>>(in, mask, bg, stats, out);
}